// Round 1
// baseline (988.724 us; speedup 1.0000x reference)
//
#include <hip/hip_runtime.h>
#include <math.h>

// ---------------- degree / normalization ----------------

__global__ void deg_init_kernel(float* __restrict__ deg, int n) {
    int i = blockIdx.x * blockDim.x + threadIdx.x;
    if (i < n) deg[i] = 1.0f;  // self-loop
}

__global__ void deg_accum_kernel(const int* __restrict__ dst, float* __restrict__ deg, int e) {
    int i = blockIdx.x * blockDim.x + threadIdx.x;
    if (i < e) atomicAdd(&deg[dst[i]], 1.0f);
}

__global__ void rsqrt_kernel(float* __restrict__ deg, int n) {
    int i = blockIdx.x * blockDim.x + threadIdx.x;
    if (i < n) deg[i] = rsqrtf(deg[i]);  // deg >= 1 always
}

// ---------------- dense GEMM: Y[n,OUT] = X[n,IN] @ W[IN,OUT] ----------------

template<int IN_F, int OUT_F, int ROWS>
__global__ void gemm_kernel(const float* __restrict__ X, const float* __restrict__ W,
                            float* __restrict__ Y, int n) {
    __shared__ float Wl[IN_F * OUT_F];
    for (int i = threadIdx.x; i < IN_F * OUT_F; i += blockDim.x) Wl[i] = W[i];
    __syncthreads();
    int row0 = blockIdx.x * ROWS;
    for (int idx = threadIdx.x; idx < ROWS * OUT_F; idx += blockDim.x) {
        int r = row0 + idx / OUT_F;
        int c = idx % OUT_F;
        if (r < n) {
            const float* xr = X + (size_t)r * IN_F;
            float acc = 0.f;
            #pragma unroll
            for (int k = 0; k < IN_F; ++k) acc += xr[k] * Wl[k * OUT_F + c];
            Y[(size_t)r * OUT_F + c] = acc;
        }
    }
}

// ---------------- aggregation ----------------

// agg[i,:] = xw[i,:] * dis[i]^2   (self-loop contribution, also initializes buffer)
template<int F>
__global__ void self_init_kernel(const float* __restrict__ xw, const float* __restrict__ dis,
                                 float* __restrict__ agg, int n) {
    long long i = (long long)blockIdx.x * blockDim.x + threadIdx.x;
    if (i < (long long)n * F) {
        int r = (int)(i / F);
        float d = dis[r];
        agg[i] = xw[i] * (d * d);
    }
}

// agg[dst,:] += xw[src,:] * dis[src]*dis[dst]  (edge-parallel, one thread per (edge,col))
template<int F>
__global__ void scatter_kernel(const float* __restrict__ xw, const int* __restrict__ src,
                               const int* __restrict__ dst, const float* __restrict__ dis,
                               float* __restrict__ agg, int e) {
    long long tid = (long long)blockIdx.x * blockDim.x + threadIdx.x;
    if (tid < (long long)e * F) {
        int edge = (int)(tid / F);
        int c = (int)(tid % F);
        int s = src[edge];
        int d = dst[edge];
        float coef = dis[s] * dis[d];
        atomicAdd(&agg[(size_t)d * F + c], xw[(size_t)s * F + c] * coef);
    }
}

// h = relu(agg + b)
template<int F>
__global__ void bias_relu_kernel(const float* __restrict__ agg, const float* __restrict__ b,
                                 float* __restrict__ h, int n) {
    long long i = (long long)blockIdx.x * blockDim.x + threadIdx.x;
    if (i < (long long)n * F) {
        int c = (int)(i % F);
        h[i] = fmaxf(agg[i] + b[c], 0.f);
    }
}

// out[i,:] = log_softmax(agg[i,:] + b), 40 classes, one wave (64 lanes) per row
__global__ void logsoftmax_kernel(const float* __restrict__ agg, const float* __restrict__ b,
                                  float* __restrict__ out, int n) {
    int wid = (blockIdx.x * blockDim.x + threadIdx.x) >> 6;
    int lane = threadIdx.x & 63;
    if (wid >= n) return;  // wave-uniform branch
    float z = 0.f;
    float v = -INFINITY;
    if (lane < 40) {
        z = agg[(size_t)wid * 40 + lane] + b[lane];
        v = z;
    }
    #pragma unroll
    for (int off = 32; off > 0; off >>= 1) v = fmaxf(v, __shfl_xor(v, off));
    float ex = (lane < 40) ? expf(z - v) : 0.f;
    float s = ex;
    #pragma unroll
    for (int off = 32; off > 0; off >>= 1) s += __shfl_xor(s, off);
    float ls = logf(s);
    if (lane < 40) out[(size_t)wid * 40 + lane] = z - v - ls;
}

// ---------------- launch ----------------

extern "C" void kernel_launch(void* const* d_in, const int* in_sizes, int n_in,
                              void* d_out, int out_size, void* d_ws, size_t ws_size,
                              hipStream_t stream) {
    const float* x  = (const float*)d_in[0];
    const int*   ei = (const int*)d_in[1];   // [2, E] int32 (JAX x64 disabled)
    const float* W1 = (const float*)d_in[2]; // [128, 64]
    const float* b1 = (const float*)d_in[3]; // [64]
    const float* W2 = (const float*)d_in[4]; // [64, 40]
    const float* b2 = (const float*)d_in[5]; // [40]
    float* out = (float*)d_out;              // [n, 40]

    const int n = in_sizes[0] / 128;
    const int e = in_sizes[1] / 2;
    const int* src = ei;
    const int* dst = ei + e;

    // workspace layout (fp32): dis[n] | A[n*64] | B[n*64]   (~52 MB)
    float* dis = (float*)d_ws;
    float* A = dis + n;             // xw1, then h1, then agg2
    float* B = A + (size_t)n * 64;  // agg1, then xw2

    const int T = 256;
    // degrees -> dis
    deg_init_kernel<<<(n + T - 1) / T, T, 0, stream>>>(dis, n);
    deg_accum_kernel<<<(e + T - 1) / T, T, 0, stream>>>(dst, dis, e);
    rsqrt_kernel<<<(n + T - 1) / T, T, 0, stream>>>(dis, n);

    // layer 1: xw1 = x @ W1
    gemm_kernel<128, 64, 16><<<(n + 15) / 16, T, 0, stream>>>(x, W1, A, n);
    // agg1 = self + scatter
    {
        long long tot = (long long)n * 64;
        self_init_kernel<64><<<(int)((tot + T - 1) / T), T, 0, stream>>>(A, dis, B, n);
        long long etot = (long long)e * 64;
        scatter_kernel<64><<<(int)((etot + T - 1) / T), T, 0, stream>>>(A, src, dst, dis, B, e);
        bias_relu_kernel<64><<<(int)((tot + T - 1) / T), T, 0, stream>>>(B, b1, A, n);
    }

    // layer 2: xw2 = h1 @ W2 (h1 in A, xw2 into B)
    gemm_kernel<64, 40, 32><<<(n + 31) / 32, T, 0, stream>>>(A, W2, B, n);
    {
        long long tot = (long long)n * 40;
        self_init_kernel<40><<<(int)((tot + T - 1) / T), T, 0, stream>>>(B, dis, A, n);
        long long etot = (long long)e * 40;
        scatter_kernel<40><<<(int)((etot + T - 1) / T), T, 0, stream>>>(B, src, dst, dis, A, e);
    }

    // log_softmax(agg2 + b2): one 64-lane wave per row
    {
        long long threads = (long long)n * 64;
        logsoftmax_kernel<<<(int)((threads + T - 1) / T), T, 0, stream>>>(A, b2, out, n);
    }
}

// Round 2
// 674.882 us; speedup vs baseline: 1.4650x; 1.4650x over previous
//
#include <hip/hip_runtime.h>
#include <math.h>

#define SCAN_B 1024

// ---------------- CSR build ----------------

__global__ void zero_counts_kernel(int* __restrict__ c, int n) {
    int i = blockIdx.x * blockDim.x + threadIdx.x;
    if (i < n) c[i] = 0;
}

__global__ void hist_kernel(const int* __restrict__ dst, int* __restrict__ counts, int e) {
    int i = blockIdx.x * blockDim.x + threadIdx.x;
    if (i < e) atomicAdd(&counts[dst[i]], 1);
}

// dis[i] = rsqrt(deg_in + 1)   (self-loop included)
__global__ void dis_kernel(const int* __restrict__ counts, float* __restrict__ dis, int n) {
    int i = blockIdx.x * blockDim.x + threadIdx.x;
    if (i < n) dis[i] = rsqrtf((float)counts[i] + 1.0f);
}

// block-local exclusive scan of counts -> rowptr ; block totals -> bsums
__global__ void scan1_kernel(const int* __restrict__ counts, int* __restrict__ rowptr,
                             int* __restrict__ bsums, int n) {
    __shared__ int tmp[SCAN_B];
    int tid = threadIdx.x;
    int i = blockIdx.x * SCAN_B + tid;
    int v = (i < n) ? counts[i] : 0;
    tmp[tid] = v;
    __syncthreads();
    #pragma unroll
    for (int off = 1; off < SCAN_B; off <<= 1) {
        int t = (tid >= off) ? tmp[tid - off] : 0;
        __syncthreads();
        tmp[tid] += t;
        __syncthreads();
    }
    if (i < n) rowptr[i] = tmp[tid] - v;          // exclusive within block
    if (tid == SCAN_B - 1) bsums[blockIdx.x] = tmp[tid];
}

// single-block exclusive scan of bsums (nb <= SCAN_B)
__global__ void scan2_kernel(int* __restrict__ bsums, int nb) {
    __shared__ int tmp[SCAN_B];
    int tid = threadIdx.x;
    int v = (tid < nb) ? bsums[tid] : 0;
    tmp[tid] = v;
    __syncthreads();
    #pragma unroll
    for (int off = 1; off < SCAN_B; off <<= 1) {
        int t = (tid >= off) ? tmp[tid - off] : 0;
        __syncthreads();
        tmp[tid] += t;
        __syncthreads();
    }
    if (tid < nb) bsums[tid] = tmp[tid] - v;
}

// add block offsets; copy to fill-cursor array; write rowptr[n]=e
__global__ void scan3_kernel(int* __restrict__ rowptr, int* __restrict__ next,
                             const int* __restrict__ bsums, int n, int e) {
    int i = blockIdx.x * blockDim.x + threadIdx.x;
    if (i < n) {
        int r = rowptr[i] + bsums[i / SCAN_B];
        rowptr[i] = r;
        next[i] = r;
    }
    if (i == 0) rowptr[n] = e;
}

// bucket-fill: srcs sorted by dst
__global__ void fill_kernel(const int* __restrict__ src, const int* __restrict__ dst,
                            int* __restrict__ next, int* __restrict__ srcs, int e) {
    int i = blockIdx.x * blockDim.x + threadIdx.x;
    if (i < e) {
        int pos = atomicAdd(&next[dst[i]], 1);
        srcs[pos] = src[i];
    }
}

// ---------------- dense GEMM: Y[n,OUT] = X[n,IN] @ W[IN,OUT] ----------------

template<int IN_F, int OUT_F, int ROWS>
__global__ void gemm_kernel(const float* __restrict__ X, const float* __restrict__ W,
                            float* __restrict__ Y, int n) {
    __shared__ float Wl[IN_F * OUT_F];
    for (int i = threadIdx.x; i < IN_F * OUT_F; i += blockDim.x) Wl[i] = W[i];
    __syncthreads();
    int row0 = blockIdx.x * ROWS;
    for (int idx = threadIdx.x; idx < ROWS * OUT_F; idx += blockDim.x) {
        int r = row0 + idx / OUT_F;
        int c = idx % OUT_F;
        if (r < n) {
            const float* xr = X + (size_t)r * IN_F;
            float acc = 0.f;
            #pragma unroll
            for (int k = 0; k < IN_F; ++k) acc += xr[k] * Wl[k * OUT_F + c];
            Y[(size_t)r * OUT_F + c] = acc;
        }
    }
}

// ---------------- gather aggregation (one 64-lane wave per node) ----------------

// h[i,c] = relu( dis_i^2*xw[i,c] + sum_{s in N(i)} dis_s*dis_i*xw[s,c] + b[c] )
__global__ void gather1_kernel(const float* __restrict__ xw, const int* __restrict__ rowptr,
                               const int* __restrict__ srcs, const float* __restrict__ dis,
                               const float* __restrict__ b, float* __restrict__ h, int n) {
    int wid = (blockIdx.x * blockDim.x + threadIdx.x) >> 6;
    int lane = threadIdx.x & 63;
    if (wid >= n) return;
    int beg = rowptr[wid], end = rowptr[wid + 1];
    float di = dis[wid];
    float acc = xw[(size_t)wid * 64 + lane] * (di * di);
    for (int k0 = beg; k0 < end; k0 += 64) {
        int m = end - k0; if (m > 64) m = 64;
        int sj = 0; float dj = 0.f;
        if (lane < m) { sj = srcs[k0 + lane]; dj = dis[sj]; }
        for (int j = 0; j < m; ++j) {
            int s = __shfl(sj, j);
            float w = __shfl(dj, j) * di;
            acc = fmaf(xw[(size_t)s * 64 + lane], w, acc);
        }
    }
    h[(size_t)wid * 64 + lane] = fmaxf(acc + b[lane], 0.f);
}

// out[i,:] = log_softmax( dis_i^2*xw[i,:] + sum dis_s*dis_i*xw[s,:] + b )  (40 cols)
__global__ void gather2_kernel(const float* __restrict__ xw, const int* __restrict__ rowptr,
                               const int* __restrict__ srcs, const float* __restrict__ dis,
                               const float* __restrict__ b, float* __restrict__ out, int n) {
    int wid = (blockIdx.x * blockDim.x + threadIdx.x) >> 6;
    int lane = threadIdx.x & 63;
    if (wid >= n) return;
    int beg = rowptr[wid], end = rowptr[wid + 1];
    float di = dis[wid];
    float acc = 0.f;
    if (lane < 40) acc = xw[(size_t)wid * 40 + lane] * (di * di);
    for (int k0 = beg; k0 < end; k0 += 64) {
        int m = end - k0; if (m > 64) m = 64;
        int sj = 0; float dj = 0.f;
        if (lane < m) { sj = srcs[k0 + lane]; dj = dis[sj]; }
        for (int j = 0; j < m; ++j) {
            int s = __shfl(sj, j);
            float w = __shfl(dj, j) * di;
            if (lane < 40) acc = fmaf(xw[(size_t)s * 40 + lane], w, acc);
        }
    }
    // fused bias + log_softmax over lanes 0..39
    float z = (lane < 40) ? acc + b[lane] : -INFINITY;
    float v = z;
    #pragma unroll
    for (int off = 32; off > 0; off >>= 1) v = fmaxf(v, __shfl_xor(v, off));
    float ex = (lane < 40) ? expf(z - v) : 0.f;
    float s = ex;
    #pragma unroll
    for (int off = 32; off > 0; off >>= 1) s += __shfl_xor(s, off);
    float ls = logf(s);
    if (lane < 40) out[(size_t)wid * 40 + lane] = z - v - ls;
}

// ---------------- launch ----------------

extern "C" void kernel_launch(void* const* d_in, const int* in_sizes, int n_in,
                              void* d_out, int out_size, void* d_ws, size_t ws_size,
                              hipStream_t stream) {
    const float* x  = (const float*)d_in[0];
    const int*   ei = (const int*)d_in[1];   // [2, E] int32
    const float* W1 = (const float*)d_in[2]; // [128, 64]
    const float* b1 = (const float*)d_in[3]; // [64]
    const float* W2 = (const float*)d_in[4]; // [64, 40]
    const float* b2 = (const float*)d_in[5]; // [40]
    float* out = (float*)d_out;              // [n, 40]

    const int n = in_sizes[0] / 128;
    const int e = in_sizes[1] / 2;
    const int* src = ei;
    const int* dst = ei + e;

    // workspace layout:
    //   dis[n] f32 | counts/next[n] i32 | rowptr[n+1] i32 | bsums[1024] i32 |
    //   srcs[e] i32 | A[n*64] f32 | B[n*64] f32          (~59 MB)
    float* dis  = (float*)d_ws;
    int* counts = (int*)(dis + n);           // reused as fill cursor 'next'
    int* rowptr = counts + n;
    int* bsums  = rowptr + (n + 1);
    int* srcs   = bsums + SCAN_B;
    float* A    = (float*)(srcs + e);        // xw1, then xw2
    float* B    = A + (size_t)n * 64;        // h1

    const int T = 256;
    const int nb = (n + SCAN_B - 1) / SCAN_B;

    // --- CSR build + normalization ---
    zero_counts_kernel<<<(n + T - 1) / T, T, 0, stream>>>(counts, n);
    hist_kernel<<<(e + T - 1) / T, T, 0, stream>>>(dst, counts, e);
    dis_kernel<<<(n + T - 1) / T, T, 0, stream>>>(counts, dis, n);
    scan1_kernel<<<nb, SCAN_B, 0, stream>>>(counts, rowptr, bsums, n);
    scan2_kernel<<<1, SCAN_B, 0, stream>>>(bsums, nb);
    scan3_kernel<<<(n + T - 1) / T, T, 0, stream>>>(rowptr, counts, bsums, n, e);
    fill_kernel<<<(e + T - 1) / T, T, 0, stream>>>(src, dst, counts, srcs, e);

    // --- layer 1 ---
    gemm_kernel<128, 64, 16><<<(n + 15) / 16, T, 0, stream>>>(x, W1, A, n);
    gather1_kernel<<<(n * 64 + T - 1) / T, T, 0, stream>>>(A, rowptr, srcs, dis, b1, B, n);

    // --- layer 2 ---
    gemm_kernel<64, 40, 32><<<(n + 31) / 32, T, 0, stream>>>(B, W2, A, n);
    gather2_kernel<<<(n * 64 + T - 1) / T, T, 0, stream>>>(A, rowptr, srcs, dis, b2, out, n);
}